// Round 6
// baseline (6498.281 us; speedup 1.0000x reference)
//
#include <hip/hip_runtime.h>
#include <math.h>

#define B_ 64
#define T_ 2048
#define E_ 128
#define H_ 128
#define G3_ 384   // 3*H
#define C_ 32
#define M_ (T_ * B_)   // 131072 tokens

typedef _Float16 f16x2 __attribute__((ext_vector_type(2)));
typedef _Float16 f16x4v __attribute__((ext_vector_type(4)));
typedef _Float16 f16x8 __attribute__((ext_vector_type(8)));
typedef float f32x4 __attribute__((ext_vector_type(4)));

__device__ __forceinline__ f16x2 as_h2(unsigned int u) {
    union { unsigned int u; f16x2 h; } c; c.u = u; return c.h;
}

#if __has_builtin(__builtin_amdgcn_fdot2)
__device__ __forceinline__ float fdot2_acc(f16x2 a, f16x2 b, float c) {
    return __builtin_amdgcn_fdot2(a, b, c, false);
}
#else
__device__ __forceinline__ float fdot2_acc(f16x2 a, f16x2 b, float c) {
    return fmaf((float)a.y, (float)b.y, fmaf((float)a.x, (float)b.x, c));
}
#endif

// ---------------------------------------------------------------------------
// K1/K3: gi[m][r] = bias[r] + dot(w[r][:], row_m[:]) ; m = t*B + b
// 384 threads, one output row per thread (64 weight VGPRs).
// ---------------------------------------------------------------------------
template <bool GATHER>
__global__ __launch_bounds__(384, 1) void gates_gemm(
    const float* __restrict__ src,   // emb [V,128] or y [M,128]
    const int*   __restrict__ xidx,  // x [B,T] or nullptr
    const float* __restrict__ w,     // [384,128]
    const float* __restrict__ bias,  // [384]
    float* __restrict__ gi)          // [M,384]
{
    const int r = threadIdx.x;  // output row 0..383
    f16x2 wr[64];
    {
        const float2* w2 = (const float2*)(w + (long)r * 128);
#pragma unroll
        for (int i = 0; i < 64; i++) {
            float2 v = w2[i];
            wr[i] = (f16x2){(_Float16)v.x, (_Float16)v.y};
        }
    }
    const float br = bias[r];

    __shared__ __align__(16) f16x2 rows[8][64];   // 8 tokens x 128 f16

    for (int grp = blockIdx.x; grp < M_ / 8; grp += gridDim.x) {
        const int m0 = grp * 8;
        __syncthreads();  // protect rows[] from readers of previous iter
        for (int j = r; j < 512; j += 384) {
            const int s = j >> 6;               // token in group
            const int p = j & 63;               // f16x2 pair within row
            const int mm = m0 + s;
            long row;
            if (GATHER) {
                const int t = mm >> 6;          // m = t*B + b, B=64
                const int bb = mm & 63;
                row = (long)xidx[bb * T_ + t];
            } else {
                row = mm;
            }
            float2 v = ((const float2*)(src + row * 128))[p];
            rows[s][p] = (f16x2){(_Float16)v.x, (_Float16)v.y};
        }
        __syncthreads();
        for (int s = 0; s < 8; s++) {
            const uint4* h16 = (const uint4*)rows[s];
            float a0 = br, a1 = 0.f, a2 = 0.f, a3 = 0.f;
#pragma unroll
            for (int i = 0; i < 16; i++) {
                uint4 u = h16[i];
                a0 = fdot2_acc(wr[4*i+0], as_h2(u.x), a0);
                a1 = fdot2_acc(wr[4*i+1], as_h2(u.y), a1);
                a2 = fdot2_acc(wr[4*i+2], as_h2(u.z), a2);
                a3 = fdot2_acc(wr[4*i+3], as_h2(u.w), a3);
            }
            gi[(long)(m0 + s) * G3_ + r] = (a0 + a1) + (a2 + a3);
        }
    }
}

// ---------------------------------------------------------------------------
// K2/K4: GRU recurrence — MFMA, round-6 tuning.
// 4 workgroups x 256 threads (4 waves, one per SIMD). WG = 16 batches.
// Per step: gh[384x16] = W_hh[384x128] x h[128x16] via mfma_f32_16x16x32_f16.
// Wave w owns output h-blocks {2w, 2w+1} for all 3 gates -> 6 tiles x 4
// k-slices = 24 MFMA/wave/step (per-CU matrix work unchanged vs 8-wave, but
// LDS h-tile reads HALVE to 16 b128/step — the r5 LDS-pipe bottleneck).
// gi loads issue AFTER gate math directly into the gA/gB register sets ->
// first use (and the vmcnt wait) is 2 steps later (~1000+ cyc in flight),
// fixing r5's in-step exposed HBM latency.
// h tile in LDS [b][k] f16, XOR-swizzled (^((b&7)<<4)), double-buffered;
// ONE raw s_barrier per step, lgkmcnt-only drain.
// Fragment maps (16x16x32): A: row=l&15, k=8*(l>>4)+j ; B: col=l&15, same k;
// D: col=l&15 (batch), row=4*(l>>4)+reg (h). Verified in r5 (passed).
// ---------------------------------------------------------------------------
#define GSTEP4(CUR, NXT, GG, TT, TP)                                           \
  {                                                                            \
    const char* hbuf = Hl[CUR];                                                \
    f16x8 bfr[4];                                                              \
    _Pragma("unroll") for (int ks = 0; ks < 4; ks++)                           \
        bfr[ks] = *(const f16x8*)(hbuf + rdo[ks]);                             \
    f32x4 acc[3][2];                                                           \
    _Pragma("unroll") for (int G = 0; G < 3; G++)                              \
      _Pragma("unroll") for (int p = 0; p < 2; p++)                            \
        acc[G][p] = (f32x4){0.f, 0.f, 0.f, 0.f};                               \
    _Pragma("unroll") for (int ks = 0; ks < 4; ks++)                           \
      _Pragma("unroll") for (int G = 0; G < 3; G++)                            \
        _Pragma("unroll") for (int p = 0; p < 2; p++)                          \
          acc[G][p] = __builtin_amdgcn_mfma_f32_16x16x32_f16(                  \
              aF[G][p][ks], bfr[ks], acc[G][p], 0, 0, 0);                      \
    _Pragma("unroll") for (int p = 0; p < 2; p++) {                            \
      f16x4v hw;                                                               \
      f32x4 yv;                                                                \
      _Pragma("unroll") for (int j = 0; j < 4; j++) {                          \
        const float hr = acc[0][p][j] + bh[0][p][j];                           \
        const float hz = acc[1][p][j] + bh[1][p][j];                           \
        const float hn = acc[2][p][j] + bh[2][p][j];                           \
        const float rr = 1.f / (1.f + __expf(-(GG[0][p][j] + hr)));            \
        const float zz = 1.f / (1.f + __expf(-(GG[1][p][j] + hz)));            \
        const float na = GG[2][p][j] + rr * hn;                                \
        const float nn = 1.f - 2.f / (__expf(2.f * na) + 1.f);                 \
        const float hv = (1.f - zz) * nn + zz * hprev[p][j];                   \
        hprev[p][j] = hv; hw[j] = (_Float16)hv; yv[j] = hv;                    \
      }                                                                        \
      *(f16x4v*)(Hl[NXT] + wro[p]) = hw;                                       \
      *(f32x4*)(y + ((size_t)(TT) * B_ + bg) * H_ + d0[p]) = yv;               \
    }                                                                          \
    {                                                                          \
      const int tp = ((TP) < T_) ? (TP) : (TT);                                \
      const float* gp = gi_g + (size_t)tp * (B_ * G3_);                        \
      _Pragma("unroll") for (int G = 0; G < 3; G++)                            \
        _Pragma("unroll") for (int p = 0; p < 2; p++)                          \
          GG[G][p] = *(const f32x4*)(gp + G * 128 + d0[p]);                    \
    }                                                                          \
    asm volatile("s_waitcnt lgkmcnt(0)" ::: "memory");                         \
    __builtin_amdgcn_s_barrier();                                              \
    __builtin_amdgcn_sched_barrier(0);                                         \
  }

__global__ __launch_bounds__(256, 1) void gru_layer(
    const float* __restrict__ gi,    // [M,384]
    const float* __restrict__ w_hh,  // [384,128]
    const float* __restrict__ b_hh,  // [384]
    float* __restrict__ y)           // [M,128]
{
    const int tid = threadIdx.x;
    const int w  = tid >> 6;         // wave id 0..3 -> h-block pair {2w,2w+1}
    const int l  = tid & 63;
    const int rl = l & 15;           // A row / B col / D col within tile
    const int kg = l >> 4;           // 0..3
    const int bg = blockIdx.x * 16 + rl;       // global batch (D col)

    // A-fragments: W_hh[G*128 + (2w+p)*16 + rl][ks*32 + kg*8 + 0..7]
    f16x8 aF[3][2][4];
#pragma unroll
    for (int G = 0; G < 3; G++) {
#pragma unroll
        for (int p = 0; p < 2; p++) {
            const float* wrow = w_hh + (size_t)(G * 128 + (2 * w + p) * 16 + rl) * 128 + kg * 8;
#pragma unroll
            for (int ks = 0; ks < 4; ks++) {
                const f32x4 lo = *(const f32x4*)(wrow + ks * 32);
                const f32x4 hi = *(const f32x4*)(wrow + ks * 32 + 4);
                aF[G][p][ks] = (f16x8){(_Float16)lo[0], (_Float16)lo[1], (_Float16)lo[2], (_Float16)lo[3],
                                       (_Float16)hi[0], (_Float16)hi[1], (_Float16)hi[2], (_Float16)hi[3]};
            }
        }
    }
    int d0[2];
    d0[0] = (2 * w + 0) * 16 + kg * 4;
    d0[1] = (2 * w + 1) * 16 + kg * 4;
    f32x4 bh[3][2];
#pragma unroll
    for (int G = 0; G < 3; G++) {
#pragma unroll
        for (int p = 0; p < 2; p++)
            bh[G][p] = *(const f32x4*)(b_hh + G * 128 + d0[p]);
    }

    // h tile: [buf][b][k] f16, byte addr = b*256 + k*2, XOR-swizzled ((b&7)<<4)
    __shared__ __align__(16) char Hl[2][4096];

    *(f32x4*)(Hl[0] + tid * 16) = (f32x4){0.f, 0.f, 0.f, 0.f};

    const int swz = (rl & 7) << 4;
    int rdo[4];
#pragma unroll
    for (int ks = 0; ks < 4; ks++)
        rdo[ks] = (rl * 256 + ks * 64 + kg * 16) ^ swz;
    int wro[2];
    wro[0] = (rl * 256 + d0[0] * 2) ^ swz;
    wro[1] = (rl * 256 + d0[1] * 2) ^ swz;

    float hprev[2][4] = {{0.f, 0.f, 0.f, 0.f}, {0.f, 0.f, 0.f, 0.f}};

    const float* gi_g = gi + (size_t)bg * G3_;

    // prologue gi loads: t=0 -> gA, t=1 -> gB
    f32x4 gA[3][2], gB[3][2];
#pragma unroll
    for (int G = 0; G < 3; G++) {
#pragma unroll
        for (int p = 0; p < 2; p++) {
            gA[G][p] = *(const f32x4*)(gi_g + G * 128 + d0[p]);
            gB[G][p] = *(const f32x4*)(gi_g + (size_t)(B_ * G3_) + G * 128 + d0[p]);
        }
    }

    __syncthreads();  // one-time full drain: buf0 zero-init visible

    for (int t = 0; t < T_; t += 2) {
        GSTEP4(0, 1, gA, t,     t + 2)
        GSTEP4(1, 0, gB, t + 1, t + 3)
    }
}

// ---------------------------------------------------------------------------
// K5: out[b*T+t][c] = relu(fc_b[c] + dot(fc_w[c], y[t*B+b]))
// ---------------------------------------------------------------------------
__global__ __launch_bounds__(256, 2) void fc_relu(
    const float* __restrict__ y,     // [M,128]
    const float* __restrict__ fc_w,  // [32,128]
    const float* __restrict__ fc_b,  // [32]
    float* __restrict__ out)         // [B*T,32]
{
    const int tid = threadIdx.x;
    const int c = tid & 31;
    const int slot = tid >> 5;

    float4 wr[32];
    const float4* w4 = (const float4*)(fc_w + c * 128);
#pragma unroll
    for (int i = 0; i < 32; i++) wr[i] = w4[i];
    const float bc = fc_b[c];

    __shared__ __align__(16) float rows[8][128];

    for (int grp = blockIdx.x; grp < M_ / 8; grp += gridDim.x) {
        const int m0 = grp * 8;
        __syncthreads();
        for (int i = tid; i < 8 * 128; i += 256) {
            rows[i >> 7][i & 127] = y[(long)m0 * 128 + i];
        }
        __syncthreads();
        const float4* h4 = (const float4*)rows[slot];
        float a0 = bc, a1 = 0.f, a2 = 0.f, a3 = 0.f;
#pragma unroll
        for (int i = 0; i < 32; i += 4) {
            float4 h0 = h4[i], h1 = h4[i + 1], h2 = h4[i + 2], h3 = h4[i + 3];
            a0 = fmaf(wr[i].w, h0.w, fmaf(wr[i].z, h0.z, fmaf(wr[i].y, h0.y, fmaf(wr[i].x, h0.x, a0))));
            a1 = fmaf(wr[i+1].w, h1.w, fmaf(wr[i+1].z, h1.z, fmaf(wr[i+1].y, h1.y, fmaf(wr[i+1].x, h1.x, a1))));
            a2 = fmaf(wr[i+2].w, h2.w, fmaf(wr[i+2].z, h2.z, fmaf(wr[i+2].y, h2.y, fmaf(wr[i+2].x, h2.x, a2))));
            a3 = fmaf(wr[i+3].w, h3.w, fmaf(wr[i+3].z, h3.z, fmaf(wr[i+3].y, h3.y, fmaf(wr[i+3].x, h3.x, a3))));
        }
        float acc = (a0 + a1) + (a2 + a3);
        acc = fmaxf(acc, 0.f);
        const int m = m0 + slot;
        const int t = m >> 6;
        const int b = m & 63;
        out[((long)b * T_ + t) * C_ + c] = acc;
    }
}

// ---------------------------------------------------------------------------
extern "C" void kernel_launch(void* const* d_in, const int* in_sizes, int n_in,
                              void* d_out, int out_size, void* d_ws, size_t ws_size,
                              hipStream_t stream) {
    const int*   x     = (const int*)d_in[0];
    const float* emb   = (const float*)d_in[1];
    const float* w_ih0 = (const float*)d_in[2];
    const float* w_hh0 = (const float*)d_in[3];
    const float* b_ih0 = (const float*)d_in[4];
    const float* b_hh0 = (const float*)d_in[5];
    const float* w_ih1 = (const float*)d_in[6];
    const float* w_hh1 = (const float*)d_in[7];
    const float* b_ih1 = (const float*)d_in[8];
    const float* b_hh1 = (const float*)d_in[9];
    const float* fc_w  = (const float*)d_in[10];
    const float* fc_b  = (const float*)d_in[11];
    float* out = (float*)d_out;

    // workspace: gi [M,384] fp32 (201.3 MB, reused for both layers) + y [M,128] (67.1 MB)
    float* gi = (float*)d_ws;
    float* yb = (float*)((char*)d_ws + (size_t)M_ * G3_ * sizeof(float));

    // layer 0 input gates (embedding gather fused)
    gates_gemm<true><<<512, 384, 0, stream>>>(emb, x, w_ih0, b_ih0, gi);
    // layer 0 recurrence (MFMA, 4 WGs x 16 batches, 4 waves each)
    gru_layer<<<4, 256, 0, stream>>>(gi, w_hh0, b_hh0, yb);
    // layer 1 input gates
    gates_gemm<false><<<512, 384, 0, stream>>>(yb, nullptr, w_ih1, b_ih1, gi);
    // layer 1 recurrence
    gru_layer<<<4, 256, 0, stream>>>(gi, w_hh1, b_hh1, yb);
    // FC + ReLU
    fc_relu<<<512, 256, 0, stream>>>(yb, fc_w, fc_b, out);
}

// Round 7
// 2787.804 us; speedup vs baseline: 2.3310x; 2.3310x over previous
//
#include <hip/hip_runtime.h>
#include <math.h>

#define B_ 64
#define T_ 2048
#define E_ 128
#define H_ 128
#define G3_ 384   // 3*H
#define C_ 32
#define M_ (T_ * B_)   // 131072 tokens

typedef _Float16 f16x2 __attribute__((ext_vector_type(2)));

__device__ __forceinline__ f16x2 as_h2(unsigned int u) {
    union { unsigned int u; f16x2 h; } c; c.u = u; return c.h;
}

#if __has_builtin(__builtin_amdgcn_fdot2)
__device__ __forceinline__ float fdot2_acc(f16x2 a, f16x2 b, float c) {
    return __builtin_amdgcn_fdot2(a, b, c, false);
}
#else
__device__ __forceinline__ float fdot2_acc(f16x2 a, f16x2 b, float c) {
    return fmaf((float)a.y, (float)b.y, fmaf((float)a.x, (float)b.x, c));
}
#endif

// ---------------------------------------------------------------------------
// K1/K3: gi[m][r] = bias[r] + dot(w[r][:], row_m[:]) ; m = t*B + b
// 384 threads, one output row per thread (64 weight VGPRs).
// ---------------------------------------------------------------------------
template <bool GATHER>
__global__ __launch_bounds__(384, 1) void gates_gemm(
    const float* __restrict__ src,   // emb [V,128] or y [M,128]
    const int*   __restrict__ xidx,  // x [B,T] or nullptr
    const float* __restrict__ w,     // [384,128]
    const float* __restrict__ bias,  // [384]
    float* __restrict__ gi)          // [M,384]
{
    const int r = threadIdx.x;  // output row 0..383
    f16x2 wr[64];
    {
        const float2* w2 = (const float2*)(w + (long)r * 128);
#pragma unroll
        for (int i = 0; i < 64; i++) {
            float2 v = w2[i];
            wr[i] = (f16x2){(_Float16)v.x, (_Float16)v.y};
        }
    }
    const float br = bias[r];

    __shared__ __align__(16) f16x2 rows[8][64];   // 8 tokens x 128 f16

    for (int grp = blockIdx.x; grp < M_ / 8; grp += gridDim.x) {
        const int m0 = grp * 8;
        __syncthreads();  // protect rows[] from readers of previous iter
        for (int j = r; j < 512; j += 384) {
            const int s = j >> 6;               // token in group
            const int p = j & 63;               // f16x2 pair within row
            const int mm = m0 + s;
            long row;
            if (GATHER) {
                const int t = mm >> 6;          // m = t*B + b, B=64
                const int bb = mm & 63;
                row = (long)xidx[bb * T_ + t];
            } else {
                row = mm;
            }
            float2 v = ((const float2*)(src + row * 128))[p];
            rows[s][p] = (f16x2){(_Float16)v.x, (_Float16)v.y};
        }
        __syncthreads();
        for (int s = 0; s < 8; s++) {
            const uint4* h16 = (const uint4*)rows[s];
            float a0 = br, a1 = 0.f, a2 = 0.f, a3 = 0.f;
#pragma unroll
            for (int i = 0; i < 16; i++) {
                uint4 u = h16[i];
                a0 = fdot2_acc(wr[4*i+0], as_h2(u.x), a0);
                a1 = fdot2_acc(wr[4*i+1], as_h2(u.y), a1);
                a2 = fdot2_acc(wr[4*i+2], as_h2(u.z), a2);
                a3 = fdot2_acc(wr[4*i+3], as_h2(u.w), a3);
            }
            gi[(long)(m0 + s) * G3_ + r] = (a0 + a1) + (a2 + a3);
        }
    }
}

// ---------------------------------------------------------------------------
// K2/K4: GRU recurrence — round 7: lane-pair K-split dot2 (MFMA abandoned).
// One block per batch, 256 threads (4 waves -> all 4 SIMDs busy).
// Lanes l and l^1 co-own h-dim g = w*32 + (l>>1); each lane holds w_hh rows
// {g, g+128, g+256} restricted to K-half (l&1)*64 -> 96 weight VGPRs
// (vs r0's 192; ~100 free VGPRs let the 8 broadcast ds_read_b128 pipeline)
// and 96 dot2/thread (VALU floor 192 cyc/SIMD, half of r0's 384).
// Partial sums combine via 3 __shfl_xor(.,1) — in-register, NO extra
// barrier (the r3 mistake). Gate math replicated across the pair (free in
// SIMT). Even lane writes h (f16, double-buffered LDS); odd lane stores y.
// ONE raw s_barrier per step, lgkmcnt-only drain; gi prefetched 2 steps
// ahead directly into named registers.
// ---------------------------------------------------------------------------
#define GSTEPX(CUR, NXT, IR, IZ, INN, TT, TP)                                  \
  {                                                                            \
    const uint4* hsrc = (const uint4*)((const char*)hb[CUR] + kh * 128);       \
    float a00 = 0.f, a01 = 0.f, a10 = 0.f, a11 = 0.f, a20 = 0.f, a21 = 0.f;    \
    _Pragma("unroll")                                                          \
    for (int i = 0; i < 8; i++) {                                              \
      uint4 u = hsrc[i];                                                       \
      f16x2 ux = as_h2(u.x), uy = as_h2(u.y), uz = as_h2(u.z), uw = as_h2(u.w);\
      a00 = fdot2_acc(wr[0][4*i+0], ux, a00);                                  \
      a10 = fdot2_acc(wr[1][4*i+0], ux, a10);                                  \
      a20 = fdot2_acc(wr[2][4*i+0], ux, a20);                                  \
      a01 = fdot2_acc(wr[0][4*i+1], uy, a01);                                  \
      a11 = fdot2_acc(wr[1][4*i+1], uy, a11);                                  \
      a21 = fdot2_acc(wr[2][4*i+1], uy, a21);                                  \
      a00 = fdot2_acc(wr[0][4*i+2], uz, a00);                                  \
      a10 = fdot2_acc(wr[1][4*i+2], uz, a10);                                  \
      a20 = fdot2_acc(wr[2][4*i+2], uz, a20);                                  \
      a01 = fdot2_acc(wr[0][4*i+3], uw, a01);                                  \
      a11 = fdot2_acc(wr[1][4*i+3], uw, a11);                                  \
      a21 = fdot2_acc(wr[2][4*i+3], uw, a21);                                  \
    }                                                                          \
    const float s0 = a00 + a01, s1 = a10 + a11, s2 = a20 + a21;                \
    const float hr = s0 + __shfl_xor(s0, 1) + bg0;                             \
    const float hz = s1 + __shfl_xor(s1, 1) + bg1;                             \
    const float hn = s2 + __shfl_xor(s2, 1) + bg2;                             \
    const float rr = 1.f / (1.f + __expf(-((IR) + hr)));                       \
    const float zz = 1.f / (1.f + __expf(-((IZ) + hz)));                       \
    const float na = (INN) + rr * hn;                                          \
    const float nn = 1.f - 2.f / (__expf(2.f * na) + 1.f);                     \
    h_own = (1.f - zz) * nn + zz * h_own;                                      \
    if (kh == 0) hb[NXT][g] = (_Float16)h_own;                                 \
    else         y_g[(size_t)(TT) * (B_ * H_)] = h_own;                        \
    {                                                                          \
      const int tp = ((TP) < T_) ? (TP) : (TT);                                \
      const float* gp = gi_g + (size_t)tp * (B_ * G3_);                        \
      IR = gp[0]; IZ = gp[128]; INN = gp[256];                                 \
    }                                                                          \
    asm volatile("s_waitcnt lgkmcnt(0)" ::: "memory");                         \
    __builtin_amdgcn_s_barrier();                                              \
    __builtin_amdgcn_sched_barrier(0);                                         \
  }

__global__ __launch_bounds__(256, 1) void gru_layer(
    const float* __restrict__ gi,    // [M,384]
    const float* __restrict__ w_hh,  // [384,128]
    const float* __restrict__ b_hh,  // [384]
    float* __restrict__ y)           // [M,128]
{
    const int tid = threadIdx.x;
    const int w   = tid >> 6;        // wave 0..3
    const int l   = tid & 63;
    const int g   = w * 32 + (l >> 1);   // owned h-dim (pair-shared)
    const int kh  = l & 1;               // K-half
    const int b   = blockIdx.x;

    // weights: rows {g, g+128, g+256}, K-range [kh*64, kh*64+64)
    f16x2 wr[3][32];
#pragma unroll
    for (int G = 0; G < 3; G++) {
        const float2* w2 = (const float2*)(w_hh + (size_t)(g + 128 * G) * 128 + kh * 64);
#pragma unroll
        for (int i = 0; i < 32; i++) {
            float2 v = w2[i];
            wr[G][i] = (f16x2){(_Float16)v.x, (_Float16)v.y};
        }
    }
    const float bg0 = b_hh[g];
    const float bg1 = b_hh[g + 128];
    const float bg2 = b_hh[g + 256];

    __shared__ __align__(16) _Float16 hb[2][128];   // double-buffered h

    if (tid < 128) hb[0][tid] = (_Float16)0.f;
    float h_own = 0.f;

    const float* gi_g = gi + (size_t)b * G3_ + g;
    float* y_g = y + (size_t)b * H_ + g;

    // prologue gi prefetch: t=0 -> A, t=1 -> B
    float irA = gi_g[0], izA = gi_g[128], innA = gi_g[256];
    const float* p1 = gi_g + (size_t)(B_ * G3_);
    float irB = p1[0], izB = p1[128], innB = p1[256];

    __syncthreads();  // one-time full drain: hb[0] init visible

    for (int t = 0; t < T_; t += 2) {
        GSTEPX(0, 1, irA, izA, innA, t,     t + 2)
        GSTEPX(1, 0, irB, izB, innB, t + 1, t + 3)
    }
}

// ---------------------------------------------------------------------------
// K5: out[b*T+t][c] = relu(fc_b[c] + dot(fc_w[c], y[t*B+b]))
// ---------------------------------------------------------------------------
__global__ __launch_bounds__(256, 2) void fc_relu(
    const float* __restrict__ y,     // [M,128]
    const float* __restrict__ fc_w,  // [32,128]
    const float* __restrict__ fc_b,  // [32]
    float* __restrict__ out)         // [B*T,32]
{
    const int tid = threadIdx.x;
    const int c = tid & 31;
    const int slot = tid >> 5;

    float4 wr[32];
    const float4* w4 = (const float4*)(fc_w + c * 128);
#pragma unroll
    for (int i = 0; i < 32; i++) wr[i] = w4[i];
    const float bc = fc_b[c];

    __shared__ __align__(16) float rows[8][128];

    for (int grp = blockIdx.x; grp < M_ / 8; grp += gridDim.x) {
        const int m0 = grp * 8;
        __syncthreads();
        for (int i = tid; i < 8 * 128; i += 256) {
            rows[i >> 7][i & 127] = y[(long)m0 * 128 + i];
        }
        __syncthreads();
        const float4* h4 = (const float4*)rows[slot];
        float a0 = bc, a1 = 0.f, a2 = 0.f, a3 = 0.f;
#pragma unroll
        for (int i = 0; i < 32; i += 4) {
            float4 h0 = h4[i], h1 = h4[i + 1], h2 = h4[i + 2], h3 = h4[i + 3];
            a0 = fmaf(wr[i].w, h0.w, fmaf(wr[i].z, h0.z, fmaf(wr[i].y, h0.y, fmaf(wr[i].x, h0.x, a0))));
            a1 = fmaf(wr[i+1].w, h1.w, fmaf(wr[i+1].z, h1.z, fmaf(wr[i+1].y, h1.y, fmaf(wr[i+1].x, h1.x, a1))));
            a2 = fmaf(wr[i+2].w, h2.w, fmaf(wr[i+2].z, h2.z, fmaf(wr[i+2].y, h2.y, fmaf(wr[i+2].x, h2.x, a2))));
            a3 = fmaf(wr[i+3].w, h3.w, fmaf(wr[i+3].z, h3.z, fmaf(wr[i+3].y, h3.y, fmaf(wr[i+3].x, h3.x, a3))));
        }
        float acc = (a0 + a1) + (a2 + a3);
        acc = fmaxf(acc, 0.f);
        const int m = m0 + slot;
        const int t = m >> 6;
        const int b = m & 63;
        out[((long)b * T_ + t) * C_ + c] = acc;
    }
}

// ---------------------------------------------------------------------------
extern "C" void kernel_launch(void* const* d_in, const int* in_sizes, int n_in,
                              void* d_out, int out_size, void* d_ws, size_t ws_size,
                              hipStream_t stream) {
    const int*   x     = (const int*)d_in[0];
    const float* emb   = (const float*)d_in[1];
    const float* w_ih0 = (const float*)d_in[2];
    const float* w_hh0 = (const float*)d_in[3];
    const float* b_ih0 = (const float*)d_in[4];
    const float* b_hh0 = (const float*)d_in[5];
    const float* w_ih1 = (const float*)d_in[6];
    const float* w_hh1 = (const float*)d_in[7];
    const float* b_ih1 = (const float*)d_in[8];
    const float* b_hh1 = (const float*)d_in[9];
    const float* fc_w  = (const float*)d_in[10];
    const float* fc_b  = (const float*)d_in[11];
    float* out = (float*)d_out;

    // workspace: gi [M,384] fp32 (201.3 MB, reused for both layers) + y [M,128] (67.1 MB)
    float* gi = (float*)d_ws;
    float* yb = (float*)((char*)d_ws + (size_t)M_ * G3_ * sizeof(float));

    // layer 0 input gates (embedding gather fused)
    gates_gemm<true><<<512, 384, 0, stream>>>(emb, x, w_ih0, b_ih0, gi);
    // layer 0 recurrence (lane-pair K-split, 64 blocks x 4 waves)
    gru_layer<<<B_, 256, 0, stream>>>(gi, w_hh0, b_hh0, yb);
    // layer 1 input gates
    gates_gemm<false><<<512, 384, 0, stream>>>(yb, nullptr, w_ih1, b_ih1, gi);
    // layer 1 recurrence
    gru_layer<<<B_, 256, 0, stream>>>(gi, w_hh1, b_hh1, yb);
    // FC + ReLU
    fc_relu<<<512, 256, 0, stream>>>(yb, fc_w, fc_b, out);
}